// Round 17
// baseline (455.232 us; speedup 1.0000x reference)
//
#include <hip/hip_runtime.h>
#include <hip/hip_cooperative_groups.h>

namespace cg = cooperative_groups;

// ---------------------------------------------------------------------------
// SparseGRUBrain: N=70000, H=8, E=1.12M, B=8.
// R17: ONE cooperative kernel, 5 phases separated by grid.sync():
//   P0 zero(cnt,cursor) -> P1 hist(rank)+calT transpose -> P2 alloc
//   (block-scan + one global atomic per block) -> P3 pack_store (lane-
//   cooperative full-line 64B records {Wz,Wr,Wh,cal}) -> P4 gru (R15 body,
//   one wave per neuron, packed f32x2 math, grid-stride).
// Eliminates 5 inter-dispatch boundaries (~25-30us of launch gaps/ramp).
// Workspace (bytes):
//   [0,      280K)   cnt
//   [448K,   +4)     cursor
//   [512K,   +560K)  rowCnt (int2 per neuron: {begin, count})
//   [1280K,  +4.5M)  rank
//   [5888K,  +2.3M)  calT ((N+1) x 8 f32)
//   [8320K,  +72M)   recs (E x 64B records)
// ---------------------------------------------------------------------------

typedef float f2 __attribute__((ext_vector_type(2)));

struct GruParams {
    const int* src;
    const int* tgt;
    const float* Wz;
    const float* Wr;
    const float* Wh;
    const float* cal;
    const float* hidden;
    const float* Uz;
    const float* Ur;
    const float* Uh;
    const float* bz;
    const float* br;
    const float* bh;
    const float* proj;
    int* cnt;
    int* cursor;
    int2* rowCnt;
    int* rank;
    float* calT;
    uint4* recs;
    float* outCal;
    float* outHid;
    int N;
    int E;
};

__device__ __forceinline__ float fast_sigmoid(float x) {
    return 1.0f / (1.0f + __expf(-x));
}
__device__ __forceinline__ float fast_tanh(float x) {
    return 2.0f / (1.0f + __expf(-2.0f * x)) - 1.0f;
}

// fp32 -> bf16 bits, round-to-nearest-even
__device__ __forceinline__ unsigned bfr(float x) {
    unsigned u = __float_as_uint(x);
    return (u + 0x7fffu + ((u >> 16) & 1u)) >> 16;
}
__device__ __forceinline__ uint4 pack8(float4 a, float4 b) {
    uint4 r;
    r.x = bfr(a.x) | (bfr(a.y) << 16);
    r.y = bfr(a.z) | (bfr(a.w) << 16);
    r.z = bfr(b.x) | (bfr(b.y) << 16);
    r.w = bfr(b.z) | (bfr(b.w) << 16);
    return r;
}

// unpack 8 bf16 from uint4 into 4 float2 pairs, packed-fma with splatted c2
#define BFMA2(acc, p, c2)                                                      \
    {                                                                          \
        f2 w;                                                                  \
        w.x = __uint_as_float((p).x << 16);                                    \
        w.y = __uint_as_float((p).x & 0xffff0000u);                            \
        acc[0] = __builtin_elementwise_fma(w, c2, acc[0]);                     \
        w.x = __uint_as_float((p).y << 16);                                    \
        w.y = __uint_as_float((p).y & 0xffff0000u);                            \
        acc[1] = __builtin_elementwise_fma(w, c2, acc[1]);                     \
        w.x = __uint_as_float((p).z << 16);                                    \
        w.y = __uint_as_float((p).z & 0xffff0000u);                            \
        acc[2] = __builtin_elementwise_fma(w, c2, acc[2]);                     \
        w.x = __uint_as_float((p).w << 16);                                    \
        w.y = __uint_as_float((p).w & 0xffff0000u);                            \
        acc[3] = __builtin_elementwise_fma(w, c2, acc[3]);                     \
    }

// xor reduce-scatter over the 8 s-lanes: input v[0..7] partials per lane,
// output = fully-reduced value for element index s (lane bits 3,4,5).
__device__ __forceinline__ float rscatter(float v[8], int lane) {
    const bool s0 = (lane & 8) != 0;
    const bool s1 = (lane & 16) != 0;
    const bool s2 = (lane & 32) != 0;
    float w0, w1, w2, w3, x0, x1;
    { float k = s0 ? v[1] : v[0], g = s0 ? v[0] : v[1]; w0 = k + __shfl_xor(g, 8, 64); }
    { float k = s0 ? v[3] : v[2], g = s0 ? v[2] : v[3]; w1 = k + __shfl_xor(g, 8, 64); }
    { float k = s0 ? v[5] : v[4], g = s0 ? v[4] : v[5]; w2 = k + __shfl_xor(g, 8, 64); }
    { float k = s0 ? v[7] : v[6], g = s0 ? v[6] : v[7]; w3 = k + __shfl_xor(g, 8, 64); }
    { float k = s1 ? w1 : w0, g = s1 ? w0 : w1; x0 = k + __shfl_xor(g, 16, 64); }
    { float k = s1 ? w3 : w2, g = s1 ? w2 : w3; x1 = k + __shfl_xor(g, 16, 64); }
    float k = s2 ? x1 : x0, g = s2 ? x0 : x1;
    return k + __shfl_xor(g, 32, 64);
}

__global__ __launch_bounds__(256) void mega(GruParams P) {
    cg::grid_group grid = cg::this_grid();
    const int tid = blockIdx.x * 256 + threadIdx.x;
    const int stride = gridDim.x * 256;
    const int N = P.N;
    const int E = P.E;

    // ---------------- P0: zero cnt + cursor ----------------
    for (int i = tid; i < N; i += stride) P.cnt[i] = 0;
    if (tid == 0) *P.cursor = 0;
    grid.sync();

    // ---------------- P1: hist (rank) + calT transpose ----------------
    {
        const int histWork = (E + 3) / 4;  // > N+1 for this problem
        for (int i = tid; i < histWork; i += stride) {
            if (i <= N) {
                float4* o = (float4*)(P.calT + (size_t)i * 8);
                if (i == N) {
                    o[0] = make_float4(0.f, 0.f, 0.f, 0.f);
                    o[1] = make_float4(0.f, 0.f, 0.f, 0.f);
                } else {
                    float v[8];
#pragma unroll
                    for (int b = 0; b < 8; ++b) v[b] = P.cal[(size_t)b * N + i];
                    o[0] = make_float4(v[0], v[1], v[2], v[3]);
                    o[1] = make_float4(v[4], v[5], v[6], v[7]);
                }
            }
            int base = i * 4;
            if (base + 3 < E) {
                int4 t = *(const int4*)(P.tgt + base);
                int4 r;
                r.x = atomicAdd(&P.cnt[t.x], 1);
                r.y = atomicAdd(&P.cnt[t.y], 1);
                r.z = atomicAdd(&P.cnt[t.z], 1);
                r.w = atomicAdd(&P.cnt[t.w], 1);
                *(int4*)(P.rank + base) = r;
            } else {
                for (int k = base; k < E; ++k) rank_tail:;
                for (int k = base; k < E; ++k) P.rank[k] = atomicAdd(&P.cnt[P.tgt[k]], 1);
            }
        }
    }
    grid.sync();

    // ---------------- P2: alloc (block scan + global atomic) ----------------
    {
        __shared__ int waveSum[4];
        const int lane = threadIdx.x & 63;
        const int wid = threadIdx.x >> 6;
        const int nChunks = (N + 255) >> 8;
        for (int ch = blockIdx.x; ch < nChunks; ch += gridDim.x) {
            const int n = ch * 256 + threadIdx.x;
            int c = (n < N) ? P.cnt[n] : 0;
            int pre = c;
#pragma unroll
            for (int off = 1; off < 64; off <<= 1) {
                int v = __shfl_up(pre, off, 64);
                if (lane >= off) pre += v;
            }
            if (lane == 63) waveSum[wid] = pre;
            __syncthreads();
            if (threadIdx.x == 0) {
                int s0 = waveSum[0], s1 = waveSum[1], s2 = waveSum[2], s3 = waveSum[3];
                int base = atomicAdd(P.cursor, s0 + s1 + s2 + s3);
                waveSum[0] = base;
                waveSum[1] = base + s0;
                waveSum[2] = base + s0 + s1;
                waveSum[3] = base + s0 + s1 + s2;
            }
            __syncthreads();
            if (n < N) P.rowCnt[n] = make_int2(waveSum[wid] + (pre - c), c);
            __syncthreads();  // guard waveSum reuse across chunk iterations
        }
    }
    grid.sync();

    // ---------------- P3: pack_store (lane-cooperative, full-line) ----------
    {
        const int total = E * 4;
        for (int g = tid; g < total; g += stride) {
            int e = g >> 2;
            int q = g & 3;
            int t = P.tgt[e];
            int pos = P.rowCnt[t].x + P.rank[e];
            const float* base;
            size_t off;
            if (q == 0)      { base = P.Wz;   off = (size_t)e * 8; }
            else if (q == 1) { base = P.Wr;   off = (size_t)e * 8; }
            else if (q == 2) { base = P.Wh;   off = (size_t)e * 8; }
            else             { base = P.calT; off = (size_t)P.src[e] * 8; }
            const float4* p = (const float4*)(base + off);
            float4 a = p[0], b = p[1];
            P.recs[(size_t)pos * 4 + q] = pack8(a, b);
        }
    }
    grid.sync();

    // ---------------- P4: gru (R15 body, grid-stride over neurons) ----------
    {
        const int lane = threadIdx.x & 63;
        const int s = lane >> 3;
        const int b = lane & 7;
        const unsigned short* recsH = (const unsigned short*)P.recs;
        for (int n0 = blockIdx.x * 4; n0 < N; n0 += gridDim.x * 4) {
            const int n = n0 + (threadIdx.x >> 6);
            if (n >= N) continue;

            const int2 rc = P.rowCnt[n];
            const int start = rc.x;
            const int end = rc.x + rc.y;

            const size_t hb = ((size_t)(b * N + n)) << 3;
            const float hvS = P.hidden[hb + s];
            const int ub = (n << 6) + (s << 3);
            f2 uzr[4], urr[4], uhr[4];
#pragma unroll
            for (int k = 0; k < 4; ++k) {
                uzr[k] = ((const f2*)(P.Uz + ub))[k];
                urr[k] = ((const f2*)(P.Ur + ub))[k];
                uhr[k] = ((const f2*)(P.Uh + ub))[k];
            }
            const float bzS = P.bz[(n << 3) + s];
            const float brS = P.br[(n << 3) + s];
            const float bhS = P.bh[(n << 3) + s];
            const float pjS = P.proj[s];

            f2 az2[4], ar2[4], ah2[4];
#pragma unroll
            for (int k = 0; k < 4; ++k) {
                az2[k] = (f2){0.0f, 0.0f};
                ar2[k] = (f2){0.0f, 0.0f};
                ah2[k] = (f2){0.0f, 0.0f};
            }

            for (int j = start + s; j < end; j += 8) {
                const uint4* rp = P.recs + (size_t)j * 4;
                uint4 pz = rp[0];
                uint4 pr = rp[1];
                uint4 ph = rp[2];
                unsigned cb = recsH[((size_t)j << 5) + 24 + b];
                float c = __uint_as_float(cb << 16);
                f2 c2 = {c, c};
                BFMA2(az2, pz, c2);
                BFMA2(ar2, pr, c2);
                BFMA2(ah2, ph, c2);
            }

            f2 hv2 = {hvS, hvS};
#pragma unroll
            for (int k = 0; k < 4; ++k) {
                az2[k] = __builtin_elementwise_fma(uzr[k], hv2, az2[k]);
                ar2[k] = __builtin_elementwise_fma(urr[k], hv2, ar2[k]);
            }

            float az[8], ar[8];
#pragma unroll
            for (int k = 0; k < 4; ++k) {
                az[2 * k] = az2[k].x; az[2 * k + 1] = az2[k].y;
                ar[2 * k] = ar2[k].x; ar[2 * k + 1] = ar2[k].y;
            }
            float AZ = rscatter(az, lane);
            float AR = rscatter(ar, lane);
            float z = fast_sigmoid(AZ + bzS);
            float r = fast_sigmoid(AR + brS);
            float rhS = r * hvS;

            f2 rh2 = {rhS, rhS};
#pragma unroll
            for (int k = 0; k < 4; ++k) {
                ah2[k] = __builtin_elementwise_fma(uhr[k], rh2, ah2[k]);
            }
            float ah[8];
#pragma unroll
            for (int k = 0; k < 4; ++k) {
                ah[2 * k] = ah2[k].x; ah[2 * k + 1] = ah2[k].y;
            }
            float AH = rscatter(ah, lane);
            float ht = fast_tanh(AH + bhS);
            float hn = (1.0f - z) * hvS + z * ht;

            float cv = hn * pjS;
            cv += __shfl_xor(cv, 8, 64);
            cv += __shfl_xor(cv, 16, 64);
            cv += __shfl_xor(cv, 32, 64);

            P.outHid[hb + s] = hn;
            if (s == 0) P.outCal[b * N + n] = fmaxf(cv, 0.0f);
        }
    }
}

extern "C" void kernel_launch(void* const* d_in, const int* in_sizes, int n_in,
                              void* d_out, int out_size, void* d_ws, size_t ws_size,
                              hipStream_t stream) {
    GruParams P;
    P.cal    = (const float*)d_in[0];
    P.hidden = (const float*)d_in[1];
    P.src    = (const int*)d_in[2];
    P.tgt    = (const int*)d_in[3];
    P.Wz     = (const float*)d_in[4];
    P.Wr     = (const float*)d_in[5];
    P.Wh     = (const float*)d_in[6];
    P.Uz     = (const float*)d_in[7];
    P.Ur     = (const float*)d_in[8];
    P.Uh     = (const float*)d_in[9];
    P.bz     = (const float*)d_in[10];
    P.br     = (const float*)d_in[11];
    P.bh     = (const float*)d_in[12];
    P.proj   = (const float*)d_in[13];

    P.E = in_sizes[2];
    const int H = in_sizes[13];           // 8
    P.N = in_sizes[10] / H;               // 70000
    (void)n_in; (void)out_size; (void)ws_size;

    float* out = (float*)d_out;
    P.outCal = out;
    P.outHid = out + (size_t)in_sizes[0];

    char* ws = (char*)d_ws;
    P.cnt    = (int*)ws;
    P.cursor = (int*)(ws + (448 << 10));
    P.rowCnt = (int2*)(ws + (512 << 10));
    P.rank   = (int*)(ws + (1280 << 10));
    P.calT   = (float*)(ws + (5888 << 10));
    P.recs   = (uint4*)(ws + (8320 << 10));

    // Cooperative grid sizing: co-resident blocks per CU x CU count.
    int occ = 0;
    hipOccupancyMaxActiveBlocksPerMultiprocessor(&occ, (const void*)mega, 256, 0);
    if (occ < 1) occ = 1;
    int numCU = 256;
    hipDeviceGetAttribute(&numCU, hipDeviceAttributeMultiprocessorCount, 0);
    int gridBlocks = occ * numCU;
    int maxUseful = (P.N + 3) / 4;  // P4 is the widest consumer of blocks
    if (gridBlocks > maxUseful) gridBlocks = maxUseful;

    void* args[] = { &P };
    hipLaunchCooperativeKernel((const void*)mega, dim3(gridBlocks), dim3(256),
                               args, 0, stream);
}

// Round 18
// 182.218 us; speedup vs baseline: 2.4983x; 2.4983x over previous
//
#include <hip/hip_runtime.h>

// ---------------------------------------------------------------------------
// SparseGRUBrain: N=70000, H=8, E=1.12M, B=8.
// Pipeline (per call): memset(cnt,cursor) -> hist(+calT transpose, rank) ->
//   alloc (block scan + one global atomic per block) -> pack_store (lane-
//   cooperative full-line 64B records {Wz,Wr,Wh,cal}) -> gru_main.
// R18: gru_main as 64-thread blocks (1 wave = 1 WG, grid = N) to remove
// intra-WG straggler coupling (Poisson row degrees -> WG lifetime = max of
// 4 waves). Body identical to R15 champion (absmax control 0.03125).
// Workspace (bytes):
//   [0,      280K)   cnt
//   [448K,   +4)     cursor
//   [512K,   +560K)  rowCnt (int2 per neuron: {begin, count})
//   [1280K,  +4.5M)  rank
//   [5888K,  +2.3M)  calT ((N+1) x 8 f32)
//   [8320K,  +72M)   recs (E x 64B records)
// ---------------------------------------------------------------------------

typedef float f2 __attribute__((ext_vector_type(2)));

__device__ __forceinline__ float fast_sigmoid(float x) {
    return 1.0f / (1.0f + __expf(-x));
}
__device__ __forceinline__ float fast_tanh(float x) {
    return 2.0f / (1.0f + __expf(-2.0f * x)) - 1.0f;
}

// fp32 -> bf16 bits, round-to-nearest-even
__device__ __forceinline__ unsigned bfr(float x) {
    unsigned u = __float_as_uint(x);
    return (u + 0x7fffu + ((u >> 16) & 1u)) >> 16;
}
__device__ __forceinline__ uint4 pack8(float4 a, float4 b) {
    uint4 r;
    r.x = bfr(a.x) | (bfr(a.y) << 16);
    r.y = bfr(a.z) | (bfr(a.w) << 16);
    r.z = bfr(b.x) | (bfr(b.y) << 16);
    r.w = bfr(b.z) | (bfr(b.w) << 16);
    return r;
}

// unpack 8 bf16 from uint4 into 4 float2 pairs, packed-fma with splatted c2
#define BFMA2(acc, p, c2)                                                      \
    {                                                                          \
        f2 w;                                                                  \
        w.x = __uint_as_float((p).x << 16);                                    \
        w.y = __uint_as_float((p).x & 0xffff0000u);                            \
        acc[0] = __builtin_elementwise_fma(w, c2, acc[0]);                     \
        w.x = __uint_as_float((p).y << 16);                                    \
        w.y = __uint_as_float((p).y & 0xffff0000u);                            \
        acc[1] = __builtin_elementwise_fma(w, c2, acc[1]);                     \
        w.x = __uint_as_float((p).z << 16);                                    \
        w.y = __uint_as_float((p).z & 0xffff0000u);                            \
        acc[2] = __builtin_elementwise_fma(w, c2, acc[2]);                     \
        w.x = __uint_as_float((p).w << 16);                                    \
        w.y = __uint_as_float((p).w & 0xffff0000u);                            \
        acc[3] = __builtin_elementwise_fma(w, c2, acc[3]);                     \
    }

// cnt[t]++ per edge (atomic return = rank within bucket); threads <= N also
// build calT (transpose of calcium, row N zeroed).
__global__ void hist_kernel(const int* __restrict__ tgt, int* __restrict__ cnt,
                            int* __restrict__ rank, const float* __restrict__ cal,
                            float* __restrict__ calT, int N, int E) {
    int i = blockIdx.x * blockDim.x + threadIdx.x;
    if (i <= N) {
        float4* o = (float4*)(calT + (size_t)i * 8);
        if (i == N) {
            o[0] = make_float4(0.f, 0.f, 0.f, 0.f);
            o[1] = make_float4(0.f, 0.f, 0.f, 0.f);
        } else {
            float v[8];
#pragma unroll
            for (int b = 0; b < 8; ++b) v[b] = cal[(size_t)b * N + i];
            o[0] = make_float4(v[0], v[1], v[2], v[3]);
            o[1] = make_float4(v[4], v[5], v[6], v[7]);
        }
    }
    int base = i * 4;
    if (base + 3 < E) {
        int4 t = *(const int4*)(tgt + base);
        int4 r;
        r.x = atomicAdd(&cnt[t.x], 1);
        r.y = atomicAdd(&cnt[t.y], 1);
        r.z = atomicAdd(&cnt[t.z], 1);
        r.w = atomicAdd(&cnt[t.w], 1);
        *(int4*)(rank + base) = r;
    } else {
        for (int k = base; k < E; ++k) rank[k] = atomicAdd(&cnt[tgt[k]], 1);
    }
}

// Row allocation without a global scan: block-local exclusive scan of cnt,
// one atomicAdd(cursor, blockTotal) per block. Writes rowCnt = {begin, count}.
__global__ __launch_bounds__(256) void alloc_kernel(const int* __restrict__ cnt,
                                                    int2* __restrict__ rowCnt,
                                                    int* __restrict__ cursor, int N) {
    __shared__ int waveSum[4];
    const int n = blockIdx.x * 256 + threadIdx.x;
    const int lane = threadIdx.x & 63;
    const int wid = threadIdx.x >> 6;
    int c = (n < N) ? cnt[n] : 0;
    int pre = c;
#pragma unroll
    for (int off = 1; off < 64; off <<= 1) {
        int v = __shfl_up(pre, off, 64);
        if (lane >= off) pre += v;
    }
    if (lane == 63) waveSum[wid] = pre;
    __syncthreads();
    if (threadIdx.x == 0) {
        int s0 = waveSum[0], s1 = waveSum[1], s2 = waveSum[2], s3 = waveSum[3];
        int base = atomicAdd(cursor, s0 + s1 + s2 + s3);
        waveSum[0] = base;
        waveSum[1] = base + s0;
        waveSum[2] = base + s0 + s1;
        waveSum[3] = base + s0 + s1 + s2;
    }
    __syncthreads();
    if (n < N) rowCnt[n] = make_int2(waveSum[wid] + (pre - c), c);
}

// LANE-COOPERATIVE packer: 4 consecutive lanes own one edge. Lane q packs
// quarter q of the 64B record (q=0..2: W rows; q=3: calT[src]) and stores one
// uint4 at recs[pos*4+q] -> each record is one fully-dirty 64B line.
__global__ __launch_bounds__(256) void pack_store(
    const int* __restrict__ src, const int* __restrict__ tgt,
    const int* __restrict__ rank, const int2* __restrict__ rowCnt,
    const float* __restrict__ Wz, const float* __restrict__ Wr,
    const float* __restrict__ Wh, const float* __restrict__ calT,
    uint4* __restrict__ recs, int E) {
    int gid = blockIdx.x * 256 + threadIdx.x;
    int e = gid >> 2;
    int q = gid & 3;
    if (e >= E) return;
    int t = tgt[e];                        // broadcast across the 4 lanes
    int pos = rowCnt[t].x + rank[e];
    const float* base;
    size_t off;
    if (q == 0)      { base = Wz;   off = (size_t)e * 8; }
    else if (q == 1) { base = Wr;   off = (size_t)e * 8; }
    else if (q == 2) { base = Wh;   off = (size_t)e * 8; }
    else             { base = calT; off = (size_t)src[e] * 8; }
    const float4* p = (const float4*)(base + off);
    float4 a = p[0], b = p[1];
    recs[(size_t)pos * 4 + q] = pack8(a, b);
}

// xor reduce-scatter over the 8 s-lanes: input v[0..7] partials per lane,
// output = fully-reduced value for element index s (lane bits 3,4,5).
__device__ __forceinline__ float rscatter(float v[8], int lane) {
    const bool s0 = (lane & 8) != 0;
    const bool s1 = (lane & 16) != 0;
    const bool s2 = (lane & 32) != 0;
    float w0, w1, w2, w3, x0, x1;
    { float k = s0 ? v[1] : v[0], g = s0 ? v[0] : v[1]; w0 = k + __shfl_xor(g, 8, 64); }
    { float k = s0 ? v[3] : v[2], g = s0 ? v[2] : v[3]; w1 = k + __shfl_xor(g, 8, 64); }
    { float k = s0 ? v[5] : v[4], g = s0 ? v[4] : v[5]; w2 = k + __shfl_xor(g, 8, 64); }
    { float k = s0 ? v[7] : v[6], g = s0 ? v[6] : v[7]; w3 = k + __shfl_xor(g, 8, 64); }
    { float k = s1 ? w1 : w0, g = s1 ? w0 : w1; x0 = k + __shfl_xor(g, 16, 64); }
    { float k = s1 ? w3 : w2, g = s1 ? w2 : w3; x1 = k + __shfl_xor(g, 16, 64); }
    float k = s2 ? x1 : x0, g = s2 ? x0 : x1;
    return k + __shfl_xor(g, 32, 64);
}

// Main: ONE WAVE PER WORKGROUP (64 threads), grid = N. lane = s*8 + b.
// Body identical to R15; removes intra-WG straggler coupling entirely.
__global__ __launch_bounds__(64) void gru_main(
    const float* __restrict__ hidden, const uint4* __restrict__ recs,
    const float* __restrict__ Uz, const float* __restrict__ Ur,
    const float* __restrict__ Uh, const float* __restrict__ bz,
    const float* __restrict__ br, const float* __restrict__ bh,
    const float* __restrict__ proj, const int2* __restrict__ rowCnt,
    float* __restrict__ outCal, float* __restrict__ outHid, int N) {
    const int lane = threadIdx.x;
    const int n = blockIdx.x;
    if (n >= N) return;
    const int s = lane >> 3;  // slot / h-element index
    const int b = lane & 7;   // batch

    const int2 rc = rowCnt[n];
    const int start = rc.x;
    const int end = rc.x + rc.y;

    // ---- hoisted dense-phase loads (latency hides under the sparse loop) ----
    const size_t hb = ((size_t)(b * N + n)) << 3;
    const float hvS = hidden[hb + s];
    const int ub = (n << 6) + (s << 3);
    const f2* uz2 = (const f2*)(Uz + ub);
    const f2* ur2 = (const f2*)(Ur + ub);
    const f2* uh2 = (const f2*)(Uh + ub);
    f2 uzr[4], urr[4], uhr[4];
#pragma unroll
    for (int k = 0; k < 4; ++k) {
        uzr[k] = uz2[k];
        urr[k] = ur2[k];
        uhr[k] = uh2[k];
    }
    const float bzS = bz[(n << 3) + s];
    const float brS = br[(n << 3) + s];
    const float bhS = bh[(n << 3) + s];
    const float pjS = proj[s];

    f2 az2[4], ar2[4], ah2[4];
#pragma unroll
    for (int k = 0; k < 4; ++k) {
        az2[k] = (f2){0.0f, 0.0f};
        ar2[k] = (f2){0.0f, 0.0f};
        ah2[k] = (f2){0.0f, 0.0f};
    }

    // ---- sparse phase: lane s streams records j = start+s, +8, ... ----
    const unsigned short* recsH = (const unsigned short*)recs;
    for (int j = start + s; j < end; j += 8) {
        const uint4* rp = recs + (size_t)j * 4;
        uint4 pz = rp[0];
        uint4 pr = rp[1];
        uint4 ph = rp[2];
        unsigned cb = recsH[((size_t)j << 5) + 24 + b];
        float c = __uint_as_float(cb << 16);
        f2 c2 = {c, c};
        BFMA2(az2, pz, c2);
        BFMA2(ar2, pr, c2);
        BFMA2(ah2, ph, c2);
    }

    // ---- slot-parallel recurrent partials for h = s (packed) ----
    f2 hv2 = {hvS, hvS};
#pragma unroll
    for (int k = 0; k < 4; ++k) {
        az2[k] = __builtin_elementwise_fma(uzr[k], hv2, az2[k]);
        ar2[k] = __builtin_elementwise_fma(urr[k], hv2, ar2[k]);
    }

    // ---- reduce-scatter -> element-s scalars ----
    float az[8], ar[8];
#pragma unroll
    for (int k = 0; k < 4; ++k) {
        az[2 * k] = az2[k].x; az[2 * k + 1] = az2[k].y;
        ar[2 * k] = ar2[k].x; ar[2 * k + 1] = ar2[k].y;
    }
    float AZ = rscatter(az, lane);
    float AR = rscatter(ar, lane);
    float z = fast_sigmoid(AZ + bzS);
    float r = fast_sigmoid(AR + brS);
    float rhS = r * hvS;

    f2 rh2 = {rhS, rhS};
#pragma unroll
    for (int k = 0; k < 4; ++k) {
        ah2[k] = __builtin_elementwise_fma(uhr[k], rh2, ah2[k]);
    }
    float ah[8];
#pragma unroll
    for (int k = 0; k < 4; ++k) {
        ah[2 * k] = ah2[k].x; ah[2 * k + 1] = ah2[k].y;
    }
    float AH = rscatter(ah, lane);
    float ht = fast_tanh(AH + bhS);
    float hn = (1.0f - z) * hvS + z * ht;

    // ---- projection: butterfly all-reduce over s ----
    float cv = hn * pjS;
    cv += __shfl_xor(cv, 8, 64);
    cv += __shfl_xor(cv, 16, 64);
    cv += __shfl_xor(cv, 32, 64);

    outHid[hb + s] = hn;
    if (s == 0) outCal[b * N + n] = fmaxf(cv, 0.0f);
}

extern "C" void kernel_launch(void* const* d_in, const int* in_sizes, int n_in,
                              void* d_out, int out_size, void* d_ws, size_t ws_size,
                              hipStream_t stream) {
    const float* calcium = (const float*)d_in[0];
    const float* hidden  = (const float*)d_in[1];
    const int*   src     = (const int*)d_in[2];
    const int*   tgt     = (const int*)d_in[3];
    const float* Wz      = (const float*)d_in[4];
    const float* Wr      = (const float*)d_in[5];
    const float* Wh      = (const float*)d_in[6];
    const float* Uz      = (const float*)d_in[7];
    const float* Ur      = (const float*)d_in[8];
    const float* Uh      = (const float*)d_in[9];
    const float* bz      = (const float*)d_in[10];
    const float* br      = (const float*)d_in[11];
    const float* bh      = (const float*)d_in[12];
    const float* proj    = (const float*)d_in[13];

    const int E = in_sizes[2];
    const int H = in_sizes[13];           // 8
    const int N = in_sizes[10] / H;       // 70000
    (void)n_in; (void)out_size; (void)ws_size;

    float* out = (float*)d_out;
    float* outCal = out;
    float* outHid = out + (size_t)in_sizes[0];

    char* ws = (char*)d_ws;
    int*   cnt    = (int*)ws;
    int*   cursor = (int*)(ws + (448 << 10));
    int2*  rowCnt = (int2*)(ws + (512 << 10));
    int*   rank   = (int*)(ws + (1280 << 10));
    float* calT   = (float*)(ws + (5888 << 10));
    uint4* recs   = (uint4*)(ws + (8320 << 10));

    // zero cnt [0,280K) and cursor (at 448K) in one memset
    hipMemsetAsync(ws, 0, (448 << 10) + 4, stream);

    int histThreads = (E + 3) / 4;  // 280000 >= N+1, covers calT duty too
    hist_kernel<<<(histThreads + 255) / 256, 256, 0, stream>>>(
        tgt, cnt, rank, calcium, calT, N, E);
    alloc_kernel<<<(N + 255) / 256, 256, 0, stream>>>(cnt, rowCnt, cursor, N);
    {
        long long pthreads = (long long)E * 4;
        pack_store<<<(int)((pthreads + 255) / 256), 256, 0, stream>>>(
            src, tgt, rank, rowCnt, Wz, Wr, Wh, calT, recs, E);
    }
    gru_main<<<N, 64, 0, stream>>>(
        hidden, recs, Uz, Ur, Uh, bz, br, bh, proj,
        rowCnt, outCal, outHid, N);
}